// Round 4
// baseline (489.320 us; speedup 1.0000x reference)
//
#include <hip/hip_runtime.h>
#include <hip/hip_bf16.h>

#define DM 256
#define NB 128
#define SQ 384
#define SK 384

typedef __bf16 bf16x4 __attribute__((ext_vector_type(4)));
typedef __bf16 bf16x8 __attribute__((ext_vector_type(8)));
typedef float f32x4 __attribute__((ext_vector_type(4)));
typedef unsigned short u16;
typedef unsigned int u32;

union BF8 { bf16x8 v8; bf16x4 v4[2]; uint2 u2[2]; };

__device__ __forceinline__ u16 f2bf(float f) {
    union { float fv; u32 u; } v; v.fv = f;
    u32 r = v.u + 0x7FFFu + ((v.u >> 16) & 1u);
    return (u16)(r >> 16);
}
__device__ __forceinline__ float bf2f(u16 u) {
    union { u32 v; float f; } x; x.v = ((u32)u) << 16; return x.f;
}
__device__ __forceinline__ uint2 pack4(float a, float b, float c, float d) {
    uint2 r;
    r.x = (u32)f2bf(a) | ((u32)f2bf(b) << 16);
    r.y = (u32)f2bf(c) | ((u32)f2bf(d) << 16);
    return r;
}

// ---------------------------------------------------------------------------
// prep_w: W[k][n] fp32 -> Wt[n][k] bf16 (scale folded for q_w). 5 matrices.
// ---------------------------------------------------------------------------
__global__ __launch_bounds__(256)
void prep_w(const float* __restrict__ q_w, const float* __restrict__ k_w,
            const float* __restrict__ v_w, const float* __restrict__ g_w,
            const float* __restrict__ o_w, u16* __restrict__ wt)
{
    __shared__ float t[64][65];
    const int mat = blockIdx.z;
    const float* src = mat == 0 ? q_w : mat == 1 ? k_w : mat == 2 ? v_w : mat == 3 ? g_w : o_w;
    const float scale = (mat == 0) ? 0.17677669529663687f : 1.0f;
    const int k0 = blockIdx.x * 64, n0 = blockIdx.y * 64;
    const int tid = threadIdx.x;
#pragma unroll
    for (int i = 0; i < 4; ++i) {
        int pos = tid + i * 256;
        int r = pos >> 4, c4 = (pos & 15) * 4;
        f32x4 v = *(const f32x4*)&src[(size_t)(k0 + r) * DM + n0 + c4];
        t[r][c4 + 0] = v[0]; t[r][c4 + 1] = v[1]; t[r][c4 + 2] = v[2]; t[r][c4 + 3] = v[3];
    }
    __syncthreads();
    const int nr = tid >> 2, kq = (tid & 3) * 16;
    u16* dst = wt + (size_t)mat * DM * DM + (size_t)(n0 + nr) * DM + k0 + kq;
#pragma unroll
    for (int j = 0; j < 16; j += 4) {
        uint2 p = pack4(t[kq + j][nr] * scale, t[kq + j + 1][nr] * scale,
                        t[kq + j + 2][nr] * scale, t[kq + j + 3][nr] * scale);
        *(uint2*)&dst[j] = p;
    }
}

// ---------------------------------------------------------------------------
// proj_kernel: out = A[M,256] @ W[256,256] (+epilogue). A-frags in registers
// (A read once from HBM), Wt slabs staged in swizzled LDS.
// MODE 0: A=q_data fp32; sl<4: qb=bf16(q*scale fold), sl>=4: gate=bf16 sigmoid
// MODE 1: A=m_data fp32; sl<4: kb natural, sl>=4: v -> vT[b][c][kk] transposed
// MODE 2: A=wavg bf16;   4 slabs: out fp32 + o_bias
// ---------------------------------------------------------------------------
template<int MODE>
__global__ __launch_bounds__(256)
void proj_kernel(const float* __restrict__ Af, const u16* __restrict__ Abf,
                 const u16* __restrict__ Wt1, const u16* __restrict__ Wt2,
                 const float* __restrict__ gb, const float* __restrict__ ob,
                 u16* __restrict__ out1, u16* __restrict__ gate,
                 u16* __restrict__ vT, float* __restrict__ outf)
{
    __shared__ u16 Wlds[64 * 256];   // [n 64][k 256 permuted] XOR-swizzled
    const int tid = threadIdx.x, lane = tid & 63, w = tid >> 6;
    const int lr = lane & 15, lg = lane >> 4;
    const int m0 = blockIdx.x * 64;

    // A fragments: af[ks] covers k = ks*32 + {4lg+j, 16+4lg+j}, row m0+w*16+lr
    BF8 af[8];
    if (MODE <= 1) {
        const float* arow = Af + (size_t)(m0 + w * 16 + lr) * DM + 4 * lg;
#pragma unroll
        for (int ks = 0; ks < 8; ++ks) {
            f32x4 v0 = *(const f32x4*)&arow[ks * 32];
            f32x4 v1 = *(const f32x4*)&arow[ks * 32 + 16];
            af[ks].u2[0] = pack4(v0[0], v0[1], v0[2], v0[3]);
            af[ks].u2[1] = pack4(v1[0], v1[1], v1[2], v1[3]);
        }
    } else {
        const u16* arow = Abf + (size_t)(m0 + w * 16 + lr) * DM + 4 * lg;
#pragma unroll
        for (int ks = 0; ks < 8; ++ks) {
            af[ks].u2[0] = *(const uint2*)&arow[ks * 32];
            af[ks].u2[1] = *(const uint2*)&arow[ks * 32 + 16];
        }
    }

    const int NSLAB = (MODE == 2) ? 4 : 8;
    for (int sl = 0; sl < NSLAB; ++sl) {
        const u16* Wsrc = (sl < 4) ? Wt1 : Wt2;
        const int n0 = (sl & 3) * 64;
        if (sl) __syncthreads();
        // stage Wt slab: 64 n-rows x 256 k, permuted-contiguous + XOR swizzle
        // 64 rows x 32 chunks of 8 u16 = 2048 chunks; 256 thr x 8 iters.
#pragma unroll
        for (int i = 0; i < 8; ++i) {
            int pos = tid + i * 256;
            int nr = pos >> 5, c8 = (pos & 31) * 8;
            uint4 gv = *(const uint4*)&Wsrc[(size_t)(n0 + nr) * DM + c8];
            int within = c8 & 31;
            int pa2 = (c8 >> 5) * 64 + ((within >> 3) & 1) * 32 + (within >> 4) * 8;
            int sw = (nr & 7) << 4;
            char* rb_ = (char*)Wlds + nr * 512;
            *(uint2*)(rb_ + (pa2 ^ sw)) = make_uint2(gv.x, gv.y);
            *(uint2*)(rb_ + ((pa2 + 16) ^ sw)) = make_uint2(gv.z, gv.w);
        }
        __syncthreads();

        f32x4 acc[4];
#pragma unroll
        for (int nf = 0; nf < 4; ++nf) acc[nf] = (f32x4){0.f, 0.f, 0.f, 0.f};
#pragma unroll
        for (int ks = 0; ks < 8; ++ks) {
#pragma unroll
            for (int nf = 0; nf < 4; ++nf) {
                int row = nf * 16 + lr;
                bf16x8 bfr = *(const bf16x8*)((char*)Wlds + row * 512 +
                                              ((ks * 64 + lg * 16) ^ ((row & 7) << 4)));
                acc[nf] = __builtin_amdgcn_mfma_f32_16x16x32_bf16(af[ks].v8, bfr, acc[nf], 0, 0, 0);
            }
        }

        // epilogue: D row = m0+w*16+4lg+r, col = n0+nf*16+lr
#pragma unroll
        for (int nf = 0; nf < 4; ++nf) {
            int n = n0 + nf * 16 + lr;
            int gn = (sl & 3) * 64 + nf * 16 + lr;
            if (MODE == 0) {
                if (sl < 4) {
#pragma unroll
                    for (int r = 0; r < 4; ++r)
                        out1[(size_t)(m0 + w * 16 + 4 * lg + r) * DM + n] = f2bf(acc[nf][r]);
                } else {
                    float gbv = gb[gn];
#pragma unroll
                    for (int r = 0; r < 4; ++r)
                        gate[(size_t)(m0 + w * 16 + 4 * lg + r) * DM + gn] =
                            f2bf(1.f / (1.f + __expf(-(acc[nf][r] + gbv))));
                }
            } else if (MODE == 1) {
                if (sl < 4) {
#pragma unroll
                    for (int r = 0; r < 4; ++r)
                        out1[(size_t)(m0 + w * 16 + 4 * lg + r) * DM + n] = f2bf(acc[nf][r]);
                } else {
                    int bb = m0 / SQ;
                    int kkl = m0 - bb * SQ + w * 16 + 4 * lg;
                    *(uint2*)&vT[(size_t)(bb * DM + gn) * SK + kkl] =
                        pack4(acc[nf][0], acc[nf][1], acc[nf][2], acc[nf][3]);
                }
            } else {
                float obv = ob[n];
#pragma unroll
                for (int r = 0; r < 4; ++r)
                    outf[(size_t)(m0 + w * 16 + 4 * lg + r) * DM + n] = acc[nf][r] + obv;
            }
        }
    }
}

// ---------------------------------------------------------------------------
// attn: block = (b, q-tile 64) x ALL 8 heads (512 thr, wave = head).
// S^T = mfma(K,Q): D rows = k, cols = q. Pair bias staged ONCE per block
// into LDS (fp32, XOR-swizzled) -> no per-wave duplicate global loads, no
// post-MFMA global latency. nbias (4.7MB, L2-hot) loaded direct.
// P^T stays in registers and feeds PV. K/VT LDS: permuted-contig + XOR.
// LDS: K 32K + V 32K + bias 16K = 80KB -> 2 blocks/CU.
// ---------------------------------------------------------------------------
__global__ __launch_bounds__(512, 4)
void attn_kernel(const u16* __restrict__ Qb, const u16* __restrict__ Kb,
                 const u16* __restrict__ vT, const u16* __restrict__ gateb,
                 const float* __restrict__ bias, const float* __restrict__ nbias,
                 u16* __restrict__ wavg)
{
    extern __shared__ char smem[];
    u16* Klds = (u16*)smem;                 // [64 k][256 c permuted] 32KB, 512B rows
    u16* Vlds = (u16*)(smem + 32768);       // [256 c][64 k permuted] 32KB, 128B rows
    char* Blds = smem + 65536;              // [64 q][64 k] fp32 swizzled, 16KB, 256B rows

    const int tid = threadIdx.x, lane = tid & 63, h = tid >> 6;
    const int lr = lane & 15, lg = lane >> 4;
    // XCD-aware swizzle: 768 blocks = 8 XCDs x 96; same-b blocks share an XCD L2
    const int bid = blockIdx.x;
    const int swz = (bid & 7) * 96 + (bid >> 3);
    const int b = swz / 6, q0 = (swz % 6) * 64;

    // Q fragments (B-operand): q = q0+nf*16+lr, c = h*32 + {4lg+j, 16+4lg+j}
    BF8 qf[4];
    {
        const u16* qp = Qb + (size_t)(b * SQ + q0 + lr) * DM + h * 32 + 4 * lg;
#pragma unroll
        for (int nf = 0; nf < 4; ++nf) {
            qf[nf].u2[0] = *(const uint2*)&qp[nf * 16 * DM];
            qf[nf].u2[1] = *(const uint2*)&qp[nf * 16 * DM + 16];
        }
    }

    float m[4], l[4];
    f32x4 Oacc[2][4];
#pragma unroll
    for (int nf = 0; nf < 4; ++nf) {
        m[nf] = -1e30f; l[nf] = 0.f;
        Oacc[0][nf] = (f32x4){0.f, 0.f, 0.f, 0.f};
        Oacc[1][nf] = (f32x4){0.f, 0.f, 0.f, 0.f};
    }

    const float* nbrow = nbias + (size_t)h * SQ * SK;

    for (int kb = 0; kb < 6; ++kb) {
        const int k0 = kb * 64;
        __syncthreads();
        // stage bias tile [64 q][64 k] fp32, coalesced; swizzled rows (256B)
#pragma unroll
        for (int i = 0; i < 2; ++i) {
            int pos = tid + i * 512;
            int q = pos >> 4, ch = pos & 15;
            f32x4 bv = *(const f32x4*)&bias[(size_t)(b * SQ + q0 + q) * SK + k0 + ch * 4];
            *(f32x4*)(Blds + q * 256 + ((ch * 16) ^ ((q & 7) << 4))) = bv;
        }
        // stage K tile: 64 rows x 256 cols, permuted-contig + XOR swizzle
#pragma unroll
        for (int i = 0; i < 4; ++i) {
            int pos = tid + i * 512;
            int row = pos >> 5, c8 = (pos & 31) * 8;
            uint4 gv = *(const uint4*)&Kb[(size_t)(b * SK + k0 + row) * DM + c8];
            int within = c8 & 31;
            int pa2 = (c8 >> 5) * 64 + ((within >> 3) & 1) * 32 + (within >> 4) * 8;
            int sw = (row & 7) << 4;
            char* rb_ = (char*)Klds + row * 512;
            *(uint2*)(rb_ + (pa2 ^ sw)) = make_uint2(gv.x, gv.y);
            *(uint2*)(rb_ + ((pa2 + 16) ^ sw)) = make_uint2(gv.z, gv.w);
        }
        // stage VT tile: 256 rows (c) x 64 kk
#pragma unroll
        for (int i = 0; i < 4; ++i) {
            int pos = tid + i * 512;
            int row = pos >> 3, kk8 = (pos & 7) * 8;
            uint4 gv = *(const uint4*)&vT[(size_t)(b * DM + row) * SK + k0 + kk8];
            int within = kk8 & 31;
            int pa2 = (kk8 >> 5) * 64 + ((within >> 3) & 1) * 32 + (within >> 4) * 8;
            int sw = (row & 7) << 4;
            char* rb_ = (char*)Vlds + row * 128;
            *(uint2*)(rb_ + (pa2 ^ sw)) = make_uint2(gv.x, gv.y);
            *(uint2*)(rb_ + ((pa2 + 16) ^ sw)) = make_uint2(gv.z, gv.w);
        }
        __syncthreads();

        // S^T = K @ Q^T  (D: row = k-local, col = q-local)
        f32x4 st[4][4];
#pragma unroll
        for (int rb = 0; rb < 4; ++rb) {
            int row = rb * 16 + lr;
            bf16x8 kf = *(const bf16x8*)((char*)Klds + row * 512 +
                                         ((h * 64 + lg * 16) ^ ((lr & 7) << 4)));
#pragma unroll
            for (int nf = 0; nf < 4; ++nf)
                st[rb][nf] = __builtin_amdgcn_mfma_f32_16x16x32_bf16(
                    kf, qf[nf].v8, (f32x4){0.f, 0.f, 0.f, 0.f}, 0, 0, 0);
        }
        // bias from LDS (shared across heads) + nbias from global (L2-hot)
#pragma unroll
        for (int nf = 0; nf < 4; ++nf) {
            int ql = nf * 16 + lr;
            const float* np = nbrow + (size_t)(q0 + ql) * SK + k0 + 4 * lg;
#pragma unroll
            for (int rb = 0; rb < 4; ++rb) {
                f32x4 b4 = *(const f32x4*)(Blds + ql * 256 +
                                           ((rb * 64 + lg * 16) ^ ((lr & 7) << 4)));
                f32x4 n4 = *(const f32x4*)&np[rb * 16];
                st[rb][nf] += b4 + n4;
            }
        }
        // online softmax per q-column group nf
        BF8 pv[2][4];
#pragma unroll
        for (int nf = 0; nf < 4; ++nf) {
            float mx = st[0][nf][0];
#pragma unroll
            for (int rb = 0; rb < 4; ++rb)
#pragma unroll
                for (int r = 0; r < 4; ++r) mx = fmaxf(mx, st[rb][nf][r]);
            mx = fmaxf(mx, __shfl_xor(mx, 16, 64));
            mx = fmaxf(mx, __shfl_xor(mx, 32, 64));
            float mn = fmaxf(m[nf], mx);
            float corr = __expf(m[nf] - mn);
            m[nf] = mn;
            float ps = 0.f;
#pragma unroll
            for (int rb = 0; rb < 4; ++rb) {
                float p0 = __expf(st[rb][nf][0] - mn);
                float p1 = __expf(st[rb][nf][1] - mn);
                float p2 = __expf(st[rb][nf][2] - mn);
                float p3 = __expf(st[rb][nf][3] - mn);
                ps += (p0 + p1) + (p2 + p3);
                pv[rb >> 1][nf].u2[rb & 1] = pack4(p0, p1, p2, p3);
            }
            ps += __shfl_xor(ps, 16, 64);
            ps += __shfl_xor(ps, 32, 64);
            l[nf] = l[nf] * corr + ps;
            Oacc[0][nf] *= corr;
            Oacc[1][nf] *= corr;
        }
        // O^T += V^T @ P^T
#pragma unroll
        for (int kc = 0; kc < 2; ++kc) {
#pragma unroll
            for (int cf = 0; cf < 2; ++cf) {
                int row = h * 32 + cf * 16 + lr;
                bf16x8 vf = *(const bf16x8*)((char*)Vlds + row * 128 +
                                             ((kc * 64 + lg * 16) ^ ((lr & 7) << 4)));
#pragma unroll
                for (int nf = 0; nf < 4; ++nf)
                    Oacc[cf][nf] = __builtin_amdgcn_mfma_f32_16x16x32_bf16(
                        vf, pv[kc][nf].v8, Oacc[cf][nf], 0, 0, 0);
            }
        }
    }

    // epilogue: O^T D-layout: row = c-local = cf*16+4lg+r, col = q = nf*16+lr
#pragma unroll
    for (int nf = 0; nf < 4; ++nf) {
        float rl = 1.0f / l[nf];
        size_t qrow = (size_t)(b * SQ + q0 + nf * 16 + lr);
#pragma unroll
        for (int cf = 0; cf < 2; ++cf) {
            size_t idx = qrow * DM + h * 32 + cf * 16 + 4 * lg;
            uint2 g2 = *(const uint2*)&gateb[idx];
            float g0 = bf2f((u16)(g2.x & 0xffff)), g1 = bf2f((u16)(g2.x >> 16));
            float g2f = bf2f((u16)(g2.y & 0xffff)), g3 = bf2f((u16)(g2.y >> 16));
            f32x4 o = Oacc[cf][nf];
            *(uint2*)&wavg[idx] = pack4(o[0] * rl * g0, o[1] * rl * g1,
                                        o[2] * rl * g2f, o[3] * rl * g3);
        }
    }
}

// ---------------------------------------------------------------------------
extern "C" void kernel_launch(void* const* d_in, const int* in_sizes, int n_in,
                              void* d_out, int out_size, void* d_ws, size_t ws_size,
                              hipStream_t stream) {
    const float* q_data = (const float*)d_in[0];
    const float* m_data = (const float*)d_in[1];
    const float* bias   = (const float*)d_in[2];
    const float* nbias  = (const float*)d_in[3];
    const float* q_w    = (const float*)d_in[4];
    const float* k_w    = (const float*)d_in[5];
    const float* v_w    = (const float*)d_in[6];
    const float* o_w    = (const float*)d_in[7];
    const float* o_b    = (const float*)d_in[8];
    const float* g_w    = (const float*)d_in[9];
    const float* g_b    = (const float*)d_in[10];
    float* out = (float*)d_out;

    const size_t MB = (size_t)NB * SQ * DM * 2;   // 25165824 bytes per bf16 buffer
    char* ws = (char*)d_ws;
    u16* qb    = (u16*)(ws);
    u16* kb    = (u16*)(ws + MB);
    u16* vTb   = (u16*)(ws + 2 * MB);
    u16* gateb = (u16*)(ws + 3 * MB);
    u16* wavg  = (u16*)(ws + 4 * MB);
    u16* wt    = (u16*)(ws + 5 * MB);             // 5 x 128KB
    u16* Wtq = wt, *Wtk = wt + 65536, *Wtv = wt + 2 * 65536,
       *Wtg = wt + 3 * 65536, *Wto = wt + 4 * 65536;

    prep_w<<<dim3(4, 4, 5), 256, 0, stream>>>(q_w, k_w, v_w, g_w, o_w, wt);
    proj_kernel<0><<<768, 256, 0, stream>>>(q_data, nullptr, Wtq, Wtg, g_b, nullptr,
                                            qb, gateb, nullptr, nullptr);
    proj_kernel<1><<<768, 256, 0, stream>>>(m_data, nullptr, Wtk, Wtv, nullptr, nullptr,
                                            kb, nullptr, vTb, nullptr);

    const int ATTN_SMEM = 32768 + 32768 + 16384;  // 80 KB
    hipFuncSetAttribute((const void*)attn_kernel,
                        hipFuncAttributeMaxDynamicSharedMemorySize, ATTN_SMEM);
    attn_kernel<<<768, 512, ATTN_SMEM, stream>>>(qb, kb, vTb, gateb, bias, nbias, wavg);

    proj_kernel<2><<<768, 256, 0, stream>>>(nullptr, wavg, Wto, nullptr, nullptr, o_b,
                                            nullptr, nullptr, nullptr, out);
}

// Round 5
// 293.616 us; speedup vs baseline: 1.6665x; 1.6665x over previous
//
#include <hip/hip_runtime.h>
#include <hip/hip_bf16.h>

#define DM 256
#define NB 128
#define SQ 384
#define SK 384

typedef __bf16 bf16x4 __attribute__((ext_vector_type(4)));
typedef __bf16 bf16x8 __attribute__((ext_vector_type(8)));
typedef float f32x4 __attribute__((ext_vector_type(4)));
typedef unsigned short u16;
typedef unsigned int u32;

union BF8 { bf16x8 v8; bf16x4 v4[2]; uint2 u2[2]; };

__device__ __forceinline__ u16 f2bf(float f) {
    union { float fv; u32 u; } v; v.fv = f;
    u32 r = v.u + 0x7FFFu + ((v.u >> 16) & 1u);
    return (u16)(r >> 16);
}
__device__ __forceinline__ float bf2f(u16 u) {
    union { u32 v; float f; } x; x.v = ((u32)u) << 16; return x.f;
}
__device__ __forceinline__ uint2 pack4(float a, float b, float c, float d) {
    uint2 r;
    r.x = (u32)f2bf(a) | ((u32)f2bf(b) << 16);
    r.y = (u32)f2bf(c) | ((u32)f2bf(d) << 16);
    return r;
}

// ---------------------------------------------------------------------------
// prep_w: W[k][n] fp32 -> Wt[n][k] bf16 (scale folded for q_w). 5 matrices.
// ---------------------------------------------------------------------------
__global__ __launch_bounds__(256)
void prep_w(const float* __restrict__ q_w, const float* __restrict__ k_w,
            const float* __restrict__ v_w, const float* __restrict__ g_w,
            const float* __restrict__ o_w, u16* __restrict__ wt)
{
    __shared__ float t[64][65];
    const int mat = blockIdx.z;
    const float* src = mat == 0 ? q_w : mat == 1 ? k_w : mat == 2 ? v_w : mat == 3 ? g_w : o_w;
    const float scale = (mat == 0) ? 0.17677669529663687f : 1.0f;
    const int k0 = blockIdx.x * 64, n0 = blockIdx.y * 64;
    const int tid = threadIdx.x;
#pragma unroll
    for (int i = 0; i < 4; ++i) {
        int pos = tid + i * 256;
        int r = pos >> 4, c4 = (pos & 15) * 4;
        f32x4 v = *(const f32x4*)&src[(size_t)(k0 + r) * DM + n0 + c4];
        t[r][c4 + 0] = v[0]; t[r][c4 + 1] = v[1]; t[r][c4 + 2] = v[2]; t[r][c4 + 3] = v[3];
    }
    __syncthreads();
    const int nr = tid >> 2, kq = (tid & 3) * 16;
    u16* dst = wt + (size_t)mat * DM * DM + (size_t)(n0 + nr) * DM + k0 + kq;
#pragma unroll
    for (int j = 0; j < 16; j += 4) {
        uint2 p = pack4(t[kq + j][nr] * scale, t[kq + j + 1][nr] * scale,
                        t[kq + j + 2][nr] * scale, t[kq + j + 3][nr] * scale);
        *(uint2*)&dst[j] = p;
    }
}

// ---------------------------------------------------------------------------
// proj_kernel: out = A[M,256] @ W[256,256] (+epilogue). A-frags in registers
// (A read once from HBM), Wt slabs staged in swizzled LDS.
// MODE 0: A=q_data fp32; sl<4: qb=bf16(q*scale fold), sl>=4: gate=bf16 sigmoid
// MODE 1: A=m_data fp32; sl<4: kb natural, sl>=4: v -> vT[b][c][kk] transposed
// MODE 2: A=wavg bf16;   4 slabs: out fp32 + o_bias
// ---------------------------------------------------------------------------
template<int MODE>
__global__ __launch_bounds__(256)
void proj_kernel(const float* __restrict__ Af, const u16* __restrict__ Abf,
                 const u16* __restrict__ Wt1, const u16* __restrict__ Wt2,
                 const float* __restrict__ gb, const float* __restrict__ ob,
                 u16* __restrict__ out1, u16* __restrict__ gate,
                 u16* __restrict__ vT, float* __restrict__ outf)
{
    __shared__ u16 Wlds[64 * 256];   // [n 64][k 256 permuted] XOR-swizzled
    const int tid = threadIdx.x, lane = tid & 63, w = tid >> 6;
    const int lr = lane & 15, lg = lane >> 4;
    const int m0 = blockIdx.x * 64;

    // A fragments: af[ks] covers k = ks*32 + {4lg+j, 16+4lg+j}, row m0+w*16+lr
    BF8 af[8];
    if (MODE <= 1) {
        const float* arow = Af + (size_t)(m0 + w * 16 + lr) * DM + 4 * lg;
#pragma unroll
        for (int ks = 0; ks < 8; ++ks) {
            f32x4 v0 = *(const f32x4*)&arow[ks * 32];
            f32x4 v1 = *(const f32x4*)&arow[ks * 32 + 16];
            af[ks].u2[0] = pack4(v0[0], v0[1], v0[2], v0[3]);
            af[ks].u2[1] = pack4(v1[0], v1[1], v1[2], v1[3]);
        }
    } else {
        const u16* arow = Abf + (size_t)(m0 + w * 16 + lr) * DM + 4 * lg;
#pragma unroll
        for (int ks = 0; ks < 8; ++ks) {
            af[ks].u2[0] = *(const uint2*)&arow[ks * 32];
            af[ks].u2[1] = *(const uint2*)&arow[ks * 32 + 16];
        }
    }

    const int NSLAB = (MODE == 2) ? 4 : 8;
    for (int sl = 0; sl < NSLAB; ++sl) {
        const u16* Wsrc = (sl < 4) ? Wt1 : Wt2;
        const int n0 = (sl & 3) * 64;
        if (sl) __syncthreads();
        // stage Wt slab: 64 n-rows x 256 k, permuted-contiguous + XOR swizzle
        // 64 rows x 32 chunks of 8 u16 = 2048 chunks; 256 thr x 8 iters.
#pragma unroll
        for (int i = 0; i < 8; ++i) {
            int pos = tid + i * 256;
            int nr = pos >> 5, c8 = (pos & 31) * 8;
            uint4 gv = *(const uint4*)&Wsrc[(size_t)(n0 + nr) * DM + c8];
            int within = c8 & 31;
            int pa2 = (c8 >> 5) * 64 + ((within >> 3) & 1) * 32 + (within >> 4) * 8;
            int sw = (nr & 7) << 4;
            char* rb_ = (char*)Wlds + nr * 512;
            *(uint2*)(rb_ + (pa2 ^ sw)) = make_uint2(gv.x, gv.y);
            *(uint2*)(rb_ + ((pa2 + 16) ^ sw)) = make_uint2(gv.z, gv.w);
        }
        __syncthreads();

        f32x4 acc[4];
#pragma unroll
        for (int nf = 0; nf < 4; ++nf) acc[nf] = (f32x4){0.f, 0.f, 0.f, 0.f};
#pragma unroll
        for (int ks = 0; ks < 8; ++ks) {
#pragma unroll
            for (int nf = 0; nf < 4; ++nf) {
                int row = nf * 16 + lr;
                bf16x8 bfr = *(const bf16x8*)((char*)Wlds + row * 512 +
                                              ((ks * 64 + lg * 16) ^ ((row & 7) << 4)));
                acc[nf] = __builtin_amdgcn_mfma_f32_16x16x32_bf16(af[ks].v8, bfr, acc[nf], 0, 0, 0);
            }
        }

        // epilogue: D row = m0+w*16+4lg+r, col = n0+nf*16+lr
#pragma unroll
        for (int nf = 0; nf < 4; ++nf) {
            int n = n0 + nf * 16 + lr;
            int gn = (sl & 3) * 64 + nf * 16 + lr;
            if (MODE == 0) {
                if (sl < 4) {
#pragma unroll
                    for (int r = 0; r < 4; ++r)
                        out1[(size_t)(m0 + w * 16 + 4 * lg + r) * DM + n] = f2bf(acc[nf][r]);
                } else {
                    float gbv = gb[gn];
#pragma unroll
                    for (int r = 0; r < 4; ++r)
                        gate[(size_t)(m0 + w * 16 + 4 * lg + r) * DM + gn] =
                            f2bf(1.f / (1.f + __expf(-(acc[nf][r] + gbv))));
                }
            } else if (MODE == 1) {
                if (sl < 4) {
#pragma unroll
                    for (int r = 0; r < 4; ++r)
                        out1[(size_t)(m0 + w * 16 + 4 * lg + r) * DM + n] = f2bf(acc[nf][r]);
                } else {
                    int bb = m0 / SQ;
                    int kkl = m0 - bb * SQ + w * 16 + 4 * lg;
                    *(uint2*)&vT[(size_t)(bb * DM + gn) * SK + kkl] =
                        pack4(acc[nf][0], acc[nf][1], acc[nf][2], acc[nf][3]);
                }
            } else {
                float obv = ob[n];
#pragma unroll
                for (int r = 0; r < 4; ++r)
                    outf[(size_t)(m0 + w * 16 + 4 * lg + r) * DM + n] = acc[nf][r] + obv;
            }
        }
    }
}

// ---------------------------------------------------------------------------
// attn: block = (b, q-tile 64) x ALL 8 heads (512 thr, wave = head).
// S^T = mfma(K,Q): D rows = k, cols = q. Pair bias staged ONCE per block
// into LDS (fp32, XOR-swizzled). nbias (4.7MB, L2/L3-hot) loaded direct.
// P^T stays in registers and feeds PV. K/VT LDS: permuted-contig + XOR.
// LDS: K 32K + V 32K + bias 16K = 80KB -> 2 blocks/CU (LDS-limited).
// launch_bounds(512,2): VGPR cap 256 -- kernel needs ~100; (512,4) caused
// 64-VGPR cap -> scratch spills (431MB writes) in R4.
// ---------------------------------------------------------------------------
__global__ __launch_bounds__(512, 2)
void attn_kernel(const u16* __restrict__ Qb, const u16* __restrict__ Kb,
                 const u16* __restrict__ vT, const u16* __restrict__ gateb,
                 const float* __restrict__ bias, const float* __restrict__ nbias,
                 u16* __restrict__ wavg)
{
    extern __shared__ char smem[];
    u16* Klds = (u16*)smem;                 // [64 k][256 c permuted] 32KB, 512B rows
    u16* Vlds = (u16*)(smem + 32768);       // [256 c][64 k permuted] 32KB, 128B rows
    char* Blds = smem + 65536;              // [64 q][64 k] fp32 swizzled, 16KB, 256B rows

    const int tid = threadIdx.x, lane = tid & 63, h = tid >> 6;
    const int lr = lane & 15, lg = lane >> 4;
    // XCD-aware swizzle: 768 blocks = 8 XCDs x 96; same-b blocks share an XCD L2
    const int bid = blockIdx.x;
    const int swz = (bid & 7) * 96 + (bid >> 3);
    const int b = swz / 6, q0 = (swz % 6) * 64;

    // Q fragments (B-operand): q = q0+nf*16+lr, c = h*32 + {4lg+j, 16+4lg+j}
    BF8 qf[4];
    {
        const u16* qp = Qb + (size_t)(b * SQ + q0 + lr) * DM + h * 32 + 4 * lg;
#pragma unroll
        for (int nf = 0; nf < 4; ++nf) {
            qf[nf].u2[0] = *(const uint2*)&qp[nf * 16 * DM];
            qf[nf].u2[1] = *(const uint2*)&qp[nf * 16 * DM + 16];
        }
    }

    float m[4], l[4];
    f32x4 Oacc[2][4];
#pragma unroll
    for (int nf = 0; nf < 4; ++nf) {
        m[nf] = -1e30f; l[nf] = 0.f;
        Oacc[0][nf] = (f32x4){0.f, 0.f, 0.f, 0.f};
        Oacc[1][nf] = (f32x4){0.f, 0.f, 0.f, 0.f};
    }

    const float* nbrow = nbias + (size_t)h * SQ * SK;

    for (int kb = 0; kb < 6; ++kb) {
        const int k0 = kb * 64;
        __syncthreads();
        // stage bias tile [64 q][64 k] fp32, coalesced; swizzled rows (256B)
#pragma unroll
        for (int i = 0; i < 2; ++i) {
            int pos = tid + i * 512;
            int q = pos >> 4, ch = pos & 15;
            f32x4 bv = *(const f32x4*)&bias[(size_t)(b * SQ + q0 + q) * SK + k0 + ch * 4];
            *(f32x4*)(Blds + q * 256 + ((ch * 16) ^ ((q & 7) << 4))) = bv;
        }
        // stage K tile: 64 rows x 256 cols, permuted-contig + XOR swizzle
#pragma unroll
        for (int i = 0; i < 4; ++i) {
            int pos = tid + i * 512;
            int row = pos >> 5, c8 = (pos & 31) * 8;
            uint4 gv = *(const uint4*)&Kb[(size_t)(b * SK + k0 + row) * DM + c8];
            int within = c8 & 31;
            int pa2 = (c8 >> 5) * 64 + ((within >> 3) & 1) * 32 + (within >> 4) * 8;
            int sw = (row & 7) << 4;
            char* rb_ = (char*)Klds + row * 512;
            *(uint2*)(rb_ + (pa2 ^ sw)) = make_uint2(gv.x, gv.y);
            *(uint2*)(rb_ + ((pa2 + 16) ^ sw)) = make_uint2(gv.z, gv.w);
        }
        // stage VT tile: 256 rows (c) x 64 kk
#pragma unroll
        for (int i = 0; i < 4; ++i) {
            int pos = tid + i * 512;
            int row = pos >> 3, kk8 = (pos & 7) * 8;
            uint4 gv = *(const uint4*)&vT[(size_t)(b * DM + row) * SK + k0 + kk8];
            int within = kk8 & 31;
            int pa2 = (kk8 >> 5) * 64 + ((within >> 3) & 1) * 32 + (within >> 4) * 8;
            int sw = (row & 7) << 4;
            char* rb_ = (char*)Vlds + row * 128;
            *(uint2*)(rb_ + (pa2 ^ sw)) = make_uint2(gv.x, gv.y);
            *(uint2*)(rb_ + ((pa2 + 16) ^ sw)) = make_uint2(gv.z, gv.w);
        }
        __syncthreads();

        // S^T = K @ Q^T  (D: row = k-local, col = q-local)
        f32x4 st[4][4];
#pragma unroll
        for (int rb = 0; rb < 4; ++rb) {
            int row = rb * 16 + lr;
            bf16x8 kf = *(const bf16x8*)((char*)Klds + row * 512 +
                                         ((h * 64 + lg * 16) ^ ((lr & 7) << 4)));
#pragma unroll
            for (int nf = 0; nf < 4; ++nf)
                st[rb][nf] = __builtin_amdgcn_mfma_f32_16x16x32_bf16(
                    kf, qf[nf].v8, (f32x4){0.f, 0.f, 0.f, 0.f}, 0, 0, 0);
        }
        // bias from LDS (shared across heads) + nbias from global (L2-hot)
#pragma unroll
        for (int nf = 0; nf < 4; ++nf) {
            int ql = nf * 16 + lr;
            const float* np = nbrow + (size_t)(q0 + ql) * SK + k0 + 4 * lg;
#pragma unroll
            for (int rb = 0; rb < 4; ++rb) {
                f32x4 b4 = *(const f32x4*)(Blds + ql * 256 +
                                           ((rb * 64 + lg * 16) ^ ((lr & 7) << 4)));
                f32x4 n4 = *(const f32x4*)&np[rb * 16];
                st[rb][nf] += b4 + n4;
            }
        }
        // online softmax per q-column group nf
        BF8 pv[2][4];
#pragma unroll
        for (int nf = 0; nf < 4; ++nf) {
            float mx = st[0][nf][0];
#pragma unroll
            for (int rb = 0; rb < 4; ++rb)
#pragma unroll
                for (int r = 0; r < 4; ++r) mx = fmaxf(mx, st[rb][nf][r]);
            mx = fmaxf(mx, __shfl_xor(mx, 16, 64));
            mx = fmaxf(mx, __shfl_xor(mx, 32, 64));
            float mn = fmaxf(m[nf], mx);
            float corr = __expf(m[nf] - mn);
            m[nf] = mn;
            float ps = 0.f;
#pragma unroll
            for (int rb = 0; rb < 4; ++rb) {
                float p0 = __expf(st[rb][nf][0] - mn);
                float p1 = __expf(st[rb][nf][1] - mn);
                float p2 = __expf(st[rb][nf][2] - mn);
                float p3 = __expf(st[rb][nf][3] - mn);
                ps += (p0 + p1) + (p2 + p3);
                pv[rb >> 1][nf].u2[rb & 1] = pack4(p0, p1, p2, p3);
            }
            ps += __shfl_xor(ps, 16, 64);
            ps += __shfl_xor(ps, 32, 64);
            l[nf] = l[nf] * corr + ps;
            Oacc[0][nf] *= corr;
            Oacc[1][nf] *= corr;
        }
        // O^T += V^T @ P^T
#pragma unroll
        for (int kc = 0; kc < 2; ++kc) {
#pragma unroll
            for (int cf = 0; cf < 2; ++cf) {
                int row = h * 32 + cf * 16 + lr;
                bf16x8 vf = *(const bf16x8*)((char*)Vlds + row * 128 +
                                             ((kc * 64 + lg * 16) ^ ((lr & 7) << 4)));
#pragma unroll
                for (int nf = 0; nf < 4; ++nf)
                    Oacc[cf][nf] = __builtin_amdgcn_mfma_f32_16x16x32_bf16(
                        vf, pv[kc][nf].v8, Oacc[cf][nf], 0, 0, 0);
            }
        }
    }

    // epilogue: O^T D-layout: row = c-local = cf*16+4lg+r, col = q = nf*16+lr
#pragma unroll
    for (int nf = 0; nf < 4; ++nf) {
        float rl = 1.0f / l[nf];
        size_t qrow = (size_t)(b * SQ + q0 + nf * 16 + lr);
#pragma unroll
        for (int cf = 0; cf < 2; ++cf) {
            size_t idx = qrow * DM + h * 32 + cf * 16 + 4 * lg;
            uint2 g2 = *(const uint2*)&gateb[idx];
            float g0 = bf2f((u16)(g2.x & 0xffff)), g1 = bf2f((u16)(g2.x >> 16));
            float g2f = bf2f((u16)(g2.y & 0xffff)), g3 = bf2f((u16)(g2.y >> 16));
            f32x4 o = Oacc[cf][nf];
            *(uint2*)&wavg[idx] = pack4(o[0] * rl * g0, o[1] * rl * g1,
                                        o[2] * rl * g2f, o[3] * rl * g3);
        }
    }
}

// ---------------------------------------------------------------------------
extern "C" void kernel_launch(void* const* d_in, const int* in_sizes, int n_in,
                              void* d_out, int out_size, void* d_ws, size_t ws_size,
                              hipStream_t stream) {
    const float* q_data = (const float*)d_in[0];
    const float* m_data = (const float*)d_in[1];
    const float* bias   = (const float*)d_in[2];
    const float* nbias  = (const float*)d_in[3];
    const float* q_w    = (const float*)d_in[4];
    const float* k_w    = (const float*)d_in[5];
    const float* v_w    = (const float*)d_in[6];
    const float* o_w    = (const float*)d_in[7];
    const float* o_b    = (const float*)d_in[8];
    const float* g_w    = (const float*)d_in[9];
    const float* g_b    = (const float*)d_in[10];
    float* out = (float*)d_out;

    const size_t MB = (size_t)NB * SQ * DM * 2;   // 25165824 bytes per bf16 buffer
    char* ws = (char*)d_ws;
    u16* qb    = (u16*)(ws);
    u16* kb    = (u16*)(ws + MB);
    u16* vTb   = (u16*)(ws + 2 * MB);
    u16* gateb = (u16*)(ws + 3 * MB);
    u16* wavg  = (u16*)(ws + 4 * MB);
    u16* wt    = (u16*)(ws + 5 * MB);             // 5 x 128KB
    u16* Wtq = wt, *Wtk = wt + 65536, *Wtv = wt + 2 * 65536,
       *Wtg = wt + 3 * 65536, *Wto = wt + 4 * 65536;

    prep_w<<<dim3(4, 4, 5), 256, 0, stream>>>(q_w, k_w, v_w, g_w, o_w, wt);
    proj_kernel<0><<<768, 256, 0, stream>>>(q_data, nullptr, Wtq, Wtg, g_b, nullptr,
                                            qb, gateb, nullptr, nullptr);
    proj_kernel<1><<<768, 256, 0, stream>>>(m_data, nullptr, Wtk, Wtv, nullptr, nullptr,
                                            kb, nullptr, vTb, nullptr);

    const int ATTN_SMEM = 32768 + 32768 + 16384;  // 80 KB
    hipFuncSetAttribute((const void*)attn_kernel,
                        hipFuncAttributeMaxDynamicSharedMemorySize, ATTN_SMEM);
    attn_kernel<<<768, 512, ATTN_SMEM, stream>>>(qb, kb, vTb, gateb, bias, nbias, wavg);

    proj_kernel<2><<<768, 256, 0, stream>>>(nullptr, wavg, Wto, nullptr, nullptr, o_b,
                                            nullptr, nullptr, nullptr, out);
}